// Round 4
// baseline (258.561 us; speedup 1.0000x reference)
//
#include <hip/hip_runtime.h>

// Problem constants: B=64, Cin=512, Cout=512, H=W=28 (HW=784), K=8 experts.
#define NB 64
#define CIN 512
#define COUT 512
#define HW 784
#define KEXP 8

typedef __attribute__((ext_vector_type(8))) short bf16x8;   // 8 bf16 = 4 VGPR (MFMA A/B frag)
typedef __attribute__((ext_vector_type(4))) float f32x4;    // MFMA C/D frag

typedef const __attribute__((address_space(1))) unsigned int GU32;
typedef __attribute__((address_space(3))) unsigned int LU32;

__device__ __forceinline__ unsigned f2bf1(float f) {
  unsigned u = __builtin_bit_cast(unsigned, f);
  return (u + 0x7FFFu + ((u >> 16) & 1u)) >> 16;   // RNE fp32->bf16
}
__device__ __forceinline__ unsigned f2bf2(float lo, float hi) {
  return f2bf1(lo) | (f2bf1(hi) << 16);
}

// ---------------- Kernel 1: fused transpose(x)->bf16-tiled + pooled parts --
// Grid 448 = (b*7+nb). Per block: x[b][:, nb*112..+112] -> xt units
//   xt[(b*7+nb)*7168 + kk*448 + u], u = kgrp*112+col holds
//   x[b][kk*32+kgrp*8+j][nb*112+col], j=0..7 packed bf16 (k-contiguous).
// Also pooled partial sums: parts[nb][b][c] = sum over this block's 112 cols.
__global__ __launch_bounds__(256) void xtpool_kernel(const float* __restrict__ x,
                                                     uint4* __restrict__ xt,
                                                     float* __restrict__ parts) {
  __shared__ float tile[32][112];   // 14336 B
  int id = blockIdx.x;
  int b = id / 7, nb = id - b * 7;
  const float* xsrc = x + (size_t)b * (CIN * HW) + nb * 112;
  uint4* dst = xt + (size_t)id * 7168;
  int t = threadIdx.x;
  int k0 = t / 112, c0 = t - k0 * 112;              // unit t
  int t2 = 256 + t, k1 = t2 / 112, c1 = t2 - k1 * 112;  // unit 256+t (t<192)
  int pr = t >> 3, pp = t & 7;                      // pool: 8 threads per row

  for (int kk = 0; kk < 16; ++kk) {
    __syncthreads();   // protect tile from previous iteration's readers
    #pragma unroll
    for (int i = 0; i < 14; ++i) {
      int idx = t + i * 256;                        // 0..3583
      int r = idx / 112, cc = idx - r * 112;
      tile[r][cc] = xsrc[(size_t)(kk * 32 + r) * HW + cc];
    }
    __syncthreads();
    // pooled partial: row pr, threads pp=0..7 each sum 14 cols, shfl-reduce
    {
      float s = 0.f;
      #pragma unroll
      for (int i = 0; i < 14; ++i) s += tile[pr][pp * 14 + i];
      s += __shfl_xor(s, 1); s += __shfl_xor(s, 2); s += __shfl_xor(s, 4);
      if (pp == 0) parts[((size_t)nb * NB + b) * CIN + kk * 32 + pr] = s;
    }
    // pack units (k-contiguous bf16x8), natural slot order
    {
      uint4 pk;
      pk.x = f2bf2(tile[k0 * 8 + 0][c0], tile[k0 * 8 + 1][c0]);
      pk.y = f2bf2(tile[k0 * 8 + 2][c0], tile[k0 * 8 + 3][c0]);
      pk.z = f2bf2(tile[k0 * 8 + 4][c0], tile[k0 * 8 + 5][c0]);
      pk.w = f2bf2(tile[k0 * 8 + 6][c0], tile[k0 * 8 + 7][c0]);
      dst[kk * 448 + t] = pk;
    }
    if (t < 192) {
      uint4 pk;
      pk.x = f2bf2(tile[k1 * 8 + 0][c1], tile[k1 * 8 + 1][c1]);
      pk.y = f2bf2(tile[k1 * 8 + 2][c1], tile[k1 * 8 + 3][c1]);
      pk.z = f2bf2(tile[k1 * 8 + 4][c1], tile[k1 * 8 + 5][c1]);
      pk.w = f2bf2(tile[k1 * 8 + 6][c1], tile[k1 * 8 + 7][c1]);
      dst[kk * 448 + 256 + t] = pk;
    }
  }
}

// ---------------- Kernel 2: gate + sparsemax (reduces 7 pooled parts) ------
__global__ __launch_bounds__(512) void gate_kernel(const float* __restrict__ parts,
                                                   const float* __restrict__ gw,
                                                   const float* __restrict__ gb,
                                                   float* __restrict__ g) {
  __shared__ float lz[NB][KEXP];
  int t = threadIdx.x;
  int b = t >> 3, k = t & 7;
  const float4* wr = (const float4*)(gw + k * CIN);
  float s = 0.f;
  for (int c4 = 0; c4 < 128; ++c4) {
    float4 p = {0.f, 0.f, 0.f, 0.f};
    #pragma unroll
    for (int q = 0; q < 7; ++q) {
      float4 v = ((const float4*)(parts + (size_t)q * (NB * CIN) + b * CIN))[c4];
      p.x += v.x; p.y += v.y; p.z += v.z; p.w += v.w;
    }
    float4 qw = wr[c4];
    s += p.x * qw.x + p.y * qw.y + p.z * qw.z + p.w * qw.w;
  }
  lz[b][k] = s * (1.0f / 784.0f) + gb[k];
  __syncthreads();
  if (t < NB) {
    float z[8], zs[8];
    #pragma unroll
    for (int j = 0; j < 8; ++j) { z[j] = lz[t][j]; zs[j] = z[j]; }
    #pragma unroll
    for (int a = 1; a < 8; ++a) {
      float v = zs[a]; int j = a;
      while (j > 0 && zs[j - 1] < v) { zs[j] = zs[j - 1]; --j; }
      zs[j] = v;
    }
    float cums[8]; float csum = 0.f;
    #pragma unroll
    for (int j = 0; j < 8; ++j) { csum += zs[j]; cums[j] = csum; }
    int kz = 0;
    #pragma unroll
    for (int j = 0; j < 8; ++j)
      if (1.0f + (float)(j + 1) * zs[j] > cums[j]) kz = j + 1;
    float tau = (cums[kz - 1] - 1.0f) / (float)kz;
    #pragma unroll
    for (int j = 0; j < 8; ++j) g[t * 8 + j] = fmaxf(z[j] - tau, 0.0f);
  }
}

// ---------------- Kernel 3: w_eff builder (bf16, BM=256 GEMM-tiled) -------
// unit(b,o,i) = b*32768 + ((o>>8)*16 + (i>>5))*1024 + ((i>>3)&3)*256 + (o&255)
__global__ __launch_bounds__(256) void weff_kernel(const float* __restrict__ E,
                                                   const float* __restrict__ g,
                                                   uint4* __restrict__ wt) {
  __shared__ float gs[NB * KEXP];
  int t = threadIdx.x;
  ((float2*)gs)[t] = ((const float2*)g)[t];
  int o = blockIdx.x * 16 + (t & 15);
  int i = blockIdx.y * 128 + (t >> 4) * 8;
  float e[8][8];
  #pragma unroll
  for (int k = 0; k < 8; ++k) {
    const float4* p = (const float4*)(E + (size_t)k * (COUT * CIN) + (size_t)o * CIN + i);
    float4 a = p[0], c = p[1];
    e[k][0] = a.x; e[k][1] = a.y; e[k][2] = a.z; e[k][3] = a.w;
    e[k][4] = c.x; e[k][5] = c.y; e[k][6] = c.z; e[k][7] = c.w;
  }
  __syncthreads();
  int base = ((o >> 8) * 16 + (i >> 5)) * 1024 + ((i >> 3) & 3) * 256 + (o & 255);
  for (int b = 0; b < NB; ++b) {
    float acc[8] = {0, 0, 0, 0, 0, 0, 0, 0};
    #pragma unroll
    for (int k = 0; k < 8; ++k) {
      float gv = gs[b * 8 + k];
      #pragma unroll
      for (int j = 0; j < 8; ++j) acc[j] += gv * e[k][j];
    }
    uint4 pk;
    pk.x = f2bf2(acc[0], acc[1]); pk.y = f2bf2(acc[2], acc[3]);
    pk.z = f2bf2(acc[4], acc[5]); pk.w = f2bf2(acc[6], acc[7]);
    wt[(size_t)base + (size_t)b * 32768] = pk;
  }
}

// ---------------- Kernel 4: batched GEMM, BM=256 x BN=112, BK=32 ----------
// All staging via global_load_lds (A natural, B source pre-swizzled), 2-phase
// double-buffered pipeline: STAGE(kk+1) issued before compute(kk), one
// vmcnt(0)+barrier per kk.
__global__ __launch_bounds__(256) void gemm_kernel(const uint4* __restrict__ weff,
                                                   const uint4* __restrict__ xt,
                                                   float* __restrict__ out) {
  __shared__ uint4 ldsA[2][1024];  // [kgrp4][row256] (16KB each)
  __shared__ uint4 ldsB[2][448];   // [kgrp4][col112], XOR-swizzled (7KB each)
  int id = blockIdx.x;
  int xcd = id & 7, s = id >> 3;
  int bloc = s / 14, inner = s - bloc * 14;
  int b = xcd * 8 + bloc;
  int mb = inner & 1, nb = inner >> 1;

  int t = threadIdx.x;
  int lane = t & 63, w = t >> 6;
  int l15 = lane & 15, l4 = lane >> 4;

  const uint4* asrc = weff + (size_t)b * 32768 + (size_t)mb * 16384;
  const uint4* bsrc = xt + (size_t)(b * 7 + nb) * 7168;

  // B glds: wave w fills LDS slots w*64+lane (round1, all) and 256+w*64+lane
  // (round2, waves 0-2); source = unit f(slot) (XOR involution pre-applied).
  int s1 = w * 64 + lane,      fs1 = s1 ^ ((s1 >> 3) & 7);
  int s2 = 256 + w * 64 + lane, fs2 = s2 ^ ((s2 >> 3) & 7);

  f32x4 acc[4][7] = {};

#define STAGE(buf, kk)                                                          \
  do {                                                                          \
    _Pragma("unroll")                                                           \
    for (int it = 0; it < 4; ++it)                                              \
      __builtin_amdgcn_global_load_lds((GU32*)(asrc + (kk) * 1024 + it * 256 + t), \
                                       (LU32*)(&ldsA[buf][it * 256 + w * 64]), 16, 0, 0); \
    __builtin_amdgcn_global_load_lds((GU32*)(bsrc + (kk) * 448 + fs1),          \
                                     (LU32*)(&ldsB[buf][w * 64]), 16, 0, 0);    \
    if (w < 3)                                                                  \
      __builtin_amdgcn_global_load_lds((GU32*)(bsrc + (kk) * 448 + fs2),        \
                                       (LU32*)(&ldsB[buf][256 + w * 64]), 16, 0, 0); \
  } while (0)

  STAGE(0, 0);
  asm volatile("s_waitcnt vmcnt(0)");
  __syncthreads();

  for (int kk = 0; kk < 16; ++kk) {
    int cur = kk & 1;
    if (kk < 15) STAGE(cur ^ 1, kk + 1);

    bf16x8 af[4];
    #pragma unroll
    for (int m = 0; m < 4; ++m)
      af[m] = *(const bf16x8*)&ldsA[cur][l4 * 256 + w * 64 + m * 16 + l15];
    #pragma unroll
    for (int u = 0; u < 7; ++u) {
      int un = l4 * 112 + u * 16 + l15;
      bf16x8 bf = *(const bf16x8*)&ldsB[cur][un ^ ((un >> 3) & 7)];
      #pragma unroll
      for (int m = 0; m < 4; ++m)
        acc[m][u] = __builtin_amdgcn_mfma_f32_16x16x32_bf16(af[m], bf, acc[m][u], 0, 0, 0);
    }

    asm volatile("s_waitcnt vmcnt(0)");  // STAGE(kk+1) drained (hidden by MFMA)
    __syncthreads();
  }
#undef STAGE

  // epilogue: D layout col=lane&15, row=(lane>>4)*4+reg
  int orow0 = mb * 256 + w * 64 + l4 * 4;
  int col = nb * 112 + l15;
  #pragma unroll
  for (int m = 0; m < 4; ++m) {
    #pragma unroll
    for (int u = 0; u < 7; ++u) {
      float* op = out + ((size_t)b * COUT + orow0 + m * 16) * HW + col + u * 16;
      #pragma unroll
      for (int r = 0; r < 4; ++r) op[(size_t)r * HW] = acc[m][u][r];
    }
  }
}

// ---------------- launcher -------------------------------------------------
extern "C" void kernel_launch(void* const* d_in, const int* in_sizes, int n_in,
                              void* d_out, int out_size, void* d_ws, size_t ws_size,
                              hipStream_t stream) {
  const float* x        = (const float*)d_in[0];
  const float* gate_w   = (const float*)d_in[1];
  const float* gate_b   = (const float*)d_in[2];
  const float* expert_w = (const float*)d_in[3];
  float* out = (float*)d_out;

  char* ws = (char*)d_ws;
  uint4* weff   = (uint4*)ws;                               // 33,554,432 B
  uint4* xt     = (uint4*)(ws + 33554432);                  // 51,380,224 B
  float* parts  = (float*)(ws + 33554432 + 51380224);       //    917,504 B
  float* g      = (float*)(ws + 33554432 + 51380224 + 917504);  //  2,048 B

  xtpool_kernel<<<448, 256, 0, stream>>>(x, xt, parts);
  gate_kernel<<<1, 512, 0, stream>>>(parts, gate_w, gate_b, g);
  weff_kernel<<<dim3(32, 4), 256, 0, stream>>>(expert_w, g, weff);
  gemm_kernel<<<896, 256, 0, stream>>>(weff, xt, out);
}

// Round 5
// 171.486 us; speedup vs baseline: 1.5078x; 1.5078x over previous
//
#include <hip/hip_runtime.h>

// Problem constants: B=64, Cin=512, Cout=512, H=W=28 (HW=784), K=8 experts.
#define NB 64
#define CIN 512
#define COUT 512
#define HW 784
#define KEXP 8

typedef __attribute__((ext_vector_type(8))) short bf16x8;   // 8 bf16 = 4 VGPR (MFMA A/B frag)
typedef __attribute__((ext_vector_type(4))) float f32x4;    // MFMA C/D frag

typedef const __attribute__((address_space(1))) unsigned int GU32;
typedef __attribute__((address_space(3))) unsigned int LU32;

__device__ __forceinline__ unsigned f2bf1(float f) {
  unsigned u = __builtin_bit_cast(unsigned, f);
  return (u + 0x7FFFu + ((u >> 16) & 1u)) >> 16;   // RNE fp32->bf16
}
__device__ __forceinline__ unsigned f2bf2(float lo, float hi) {
  return f2bf1(lo) | (f2bf1(hi) << 16);
}

// ---------------- Kernel 1: fused transpose(x)->bf16-tiled + pooled parts --
// Grid 7168 = (b*7+nb)*16 + kk. Per block: one 32x112 tile of x[b] ->
//   xt[((b*7+nb)*16+kk)*448 + u], u=kgrp*112+col packs
//   x[b][kk*32+kgrp*8+j][nb*112+col], j=0..7 (k-contiguous bf16x8).
// Plus pooled partials parts[nb][b][kk*32+r] (sum over the 112 cols).
// One barrier per block; LDS padded [32][113] (113%32=17 -> pack's 8-row
// strided read spans 8 banks).
__global__ __launch_bounds__(256) void xtpool_kernel(const float* __restrict__ x,
                                                     uint4* __restrict__ xt,
                                                     float* __restrict__ parts) {
  __shared__ float tile[32][113];
  int id = blockIdx.x;
  int kk = id & 15, bn = id >> 4;
  int b = bn / 7, nb = bn - b * 7;
  const float* xsrc = x + (size_t)b * (CIN * HW) + (size_t)kk * 32 * HW + nb * 112;
  uint4* dst = xt + (size_t)id * 448;
  int t = threadIdx.x;

  #pragma unroll
  for (int i = 0; i < 14; ++i) {
    int idx = t + i * 256;                          // 0..3583
    int r = idx / 112, cc = idx - r * 112;
    tile[r][cc] = xsrc[(size_t)r * HW + cc];
  }
  __syncthreads();

  // pooled partial: row pr, threads pp=0..7 each sum 14 cols, shfl-reduce
  {
    int pr = t >> 3, pp = t & 7;
    float s = 0.f;
    #pragma unroll
    for (int i = 0; i < 14; ++i) s += tile[pr][pp * 14 + i];
    s += __shfl_xor(s, 1); s += __shfl_xor(s, 2); s += __shfl_xor(s, 4);
    if (pp == 0) parts[((size_t)nb * NB + b) * CIN + kk * 32 + pr] = s;
  }

  // pack units (k-contiguous bf16x8), natural slot order
  {
    int k0 = t / 112, c0 = t - k0 * 112;
    uint4 pk;
    pk.x = f2bf2(tile[k0 * 8 + 0][c0], tile[k0 * 8 + 1][c0]);
    pk.y = f2bf2(tile[k0 * 8 + 2][c0], tile[k0 * 8 + 3][c0]);
    pk.z = f2bf2(tile[k0 * 8 + 4][c0], tile[k0 * 8 + 5][c0]);
    pk.w = f2bf2(tile[k0 * 8 + 6][c0], tile[k0 * 8 + 7][c0]);
    dst[t] = pk;
  }
  if (t < 192) {
    int t2 = 256 + t, k1 = t2 / 112, c1 = t2 - k1 * 112;
    uint4 pk;
    pk.x = f2bf2(tile[k1 * 8 + 0][c1], tile[k1 * 8 + 1][c1]);
    pk.y = f2bf2(tile[k1 * 8 + 2][c1], tile[k1 * 8 + 3][c1]);
    pk.z = f2bf2(tile[k1 * 8 + 4][c1], tile[k1 * 8 + 5][c1]);
    pk.w = f2bf2(tile[k1 * 8 + 6][c1], tile[k1 * 8 + 7][c1]);
    dst[256 + t] = pk;
  }
}

// ---------------- Kernel 2: gate + sparsemax (reduces 7 pooled parts) ------
__global__ __launch_bounds__(512) void gate_kernel(const float* __restrict__ parts,
                                                   const float* __restrict__ gw,
                                                   const float* __restrict__ gb,
                                                   float* __restrict__ g) {
  __shared__ float lz[NB][KEXP];
  int t = threadIdx.x;
  int b = t >> 3, k = t & 7;
  const float4* wr = (const float4*)(gw + k * CIN);
  float s = 0.f;
  for (int c4 = 0; c4 < 128; ++c4) {
    float4 p = {0.f, 0.f, 0.f, 0.f};
    #pragma unroll
    for (int q = 0; q < 7; ++q) {
      float4 v = ((const float4*)(parts + (size_t)q * (NB * CIN) + b * CIN))[c4];
      p.x += v.x; p.y += v.y; p.z += v.z; p.w += v.w;
    }
    float4 qw = wr[c4];
    s += p.x * qw.x + p.y * qw.y + p.z * qw.z + p.w * qw.w;
  }
  lz[b][k] = s * (1.0f / 784.0f) + gb[k];
  __syncthreads();
  if (t < NB) {
    float z[8], zs[8];
    #pragma unroll
    for (int j = 0; j < 8; ++j) { z[j] = lz[t][j]; zs[j] = z[j]; }
    #pragma unroll
    for (int a = 1; a < 8; ++a) {
      float v = zs[a]; int j = a;
      while (j > 0 && zs[j - 1] < v) { zs[j] = zs[j - 1]; --j; }
      zs[j] = v;
    }
    float cums[8]; float csum = 0.f;
    #pragma unroll
    for (int j = 0; j < 8; ++j) { csum += zs[j]; cums[j] = csum; }
    int kz = 0;
    #pragma unroll
    for (int j = 0; j < 8; ++j)
      if (1.0f + (float)(j + 1) * zs[j] > cums[j]) kz = j + 1;
    float tau = (cums[kz - 1] - 1.0f) / (float)kz;
    #pragma unroll
    for (int j = 0; j < 8; ++j) g[t * 8 + j] = fmaxf(z[j] - tau, 0.0f);
  }
}

// ---------------- Kernel 3: w_eff builder (bf16, BM=256 GEMM-tiled) -------
// unit(b,o,i) = b*32768 + ((o>>8)*16 + (i>>5))*1024 + ((i>>3)&3)*256 + (o&255)
__global__ __launch_bounds__(256) void weff_kernel(const float* __restrict__ E,
                                                   const float* __restrict__ g,
                                                   uint4* __restrict__ wt) {
  __shared__ float gs[NB * KEXP];
  int t = threadIdx.x;
  ((float2*)gs)[t] = ((const float2*)g)[t];
  int o = blockIdx.x * 16 + (t & 15);
  int i = blockIdx.y * 128 + (t >> 4) * 8;
  float e[8][8];
  #pragma unroll
  for (int k = 0; k < 8; ++k) {
    const float4* p = (const float4*)(E + (size_t)k * (COUT * CIN) + (size_t)o * CIN + i);
    float4 a = p[0], c = p[1];
    e[k][0] = a.x; e[k][1] = a.y; e[k][2] = a.z; e[k][3] = a.w;
    e[k][4] = c.x; e[k][5] = c.y; e[k][6] = c.z; e[k][7] = c.w;
  }
  __syncthreads();
  int base = ((o >> 8) * 16 + (i >> 5)) * 1024 + ((i >> 3) & 3) * 256 + (o & 255);
  for (int b = 0; b < NB; ++b) {
    float acc[8] = {0, 0, 0, 0, 0, 0, 0, 0};
    #pragma unroll
    for (int k = 0; k < 8; ++k) {
      float gv = gs[b * 8 + k];
      #pragma unroll
      for (int j = 0; j < 8; ++j) acc[j] += gv * e[k][j];
    }
    uint4 pk;
    pk.x = f2bf2(acc[0], acc[1]); pk.y = f2bf2(acc[2], acc[3]);
    pk.z = f2bf2(acc[4], acc[5]); pk.w = f2bf2(acc[6], acc[7]);
    wt[(size_t)base + (size_t)b * 32768] = pk;
  }
}

// ---------------- Kernel 4: batched GEMM, BM=256 x BN=112, BK=32 ----------
// All staging via global_load_lds (A natural, B source pre-swizzled), 2-phase
// double-buffered pipeline: STAGE(kk+1) issued before compute(kk), one
// vmcnt(0)+barrier per kk.
__global__ __launch_bounds__(256) void gemm_kernel(const uint4* __restrict__ weff,
                                                   const uint4* __restrict__ xt,
                                                   float* __restrict__ out) {
  __shared__ uint4 ldsA[2][1024];  // [kgrp4][row256] (16KB each)
  __shared__ uint4 ldsB[2][448];   // [kgrp4][col112], XOR-swizzled (7KB each)
  int id = blockIdx.x;
  int xcd = id & 7, s = id >> 3;
  int bloc = s / 14, inner = s - bloc * 14;
  int b = xcd * 8 + bloc;
  int mb = inner & 1, nb = inner >> 1;

  int t = threadIdx.x;
  int lane = t & 63, w = t >> 6;
  int l15 = lane & 15, l4 = lane >> 4;

  const uint4* asrc = weff + (size_t)b * 32768 + (size_t)mb * 16384;
  const uint4* bsrc = xt + (size_t)(b * 7 + nb) * 7168;

  int s1 = w * 64 + lane,       fs1 = s1 ^ ((s1 >> 3) & 7);
  int s2 = 256 + w * 64 + lane, fs2 = s2 ^ ((s2 >> 3) & 7);

  f32x4 acc[4][7] = {};

#define STAGE(buf, kk)                                                          \
  do {                                                                          \
    _Pragma("unroll")                                                           \
    for (int it = 0; it < 4; ++it)                                              \
      __builtin_amdgcn_global_load_lds((GU32*)(asrc + (kk) * 1024 + it * 256 + t), \
                                       (LU32*)(&ldsA[buf][it * 256 + w * 64]), 16, 0, 0); \
    __builtin_amdgcn_global_load_lds((GU32*)(bsrc + (kk) * 448 + fs1),          \
                                     (LU32*)(&ldsB[buf][w * 64]), 16, 0, 0);    \
    if (w < 3)                                                                  \
      __builtin_amdgcn_global_load_lds((GU32*)(bsrc + (kk) * 448 + fs2),        \
                                       (LU32*)(&ldsB[buf][256 + w * 64]), 16, 0, 0); \
  } while (0)

  STAGE(0, 0);
  asm volatile("s_waitcnt vmcnt(0)");
  __syncthreads();

  for (int kk = 0; kk < 16; ++kk) {
    int cur = kk & 1;
    if (kk < 15) STAGE(cur ^ 1, kk + 1);

    bf16x8 af[4];
    #pragma unroll
    for (int m = 0; m < 4; ++m)
      af[m] = *(const bf16x8*)&ldsA[cur][l4 * 256 + w * 64 + m * 16 + l15];
    #pragma unroll
    for (int u = 0; u < 7; ++u) {
      int un = l4 * 112 + u * 16 + l15;
      bf16x8 bf = *(const bf16x8*)&ldsB[cur][un ^ ((un >> 3) & 7)];
      #pragma unroll
      for (int m = 0; m < 4; ++m)
        acc[m][u] = __builtin_amdgcn_mfma_f32_16x16x32_bf16(af[m], bf, acc[m][u], 0, 0, 0);
    }

    asm volatile("s_waitcnt vmcnt(0)");  // STAGE(kk+1) drained (hidden by MFMA)
    __syncthreads();
  }
#undef STAGE

  // epilogue: D layout col=lane&15, row=(lane>>4)*4+reg
  int orow0 = mb * 256 + w * 64 + l4 * 4;
  int col = nb * 112 + l15;
  #pragma unroll
  for (int m = 0; m < 4; ++m) {
    #pragma unroll
    for (int u = 0; u < 7; ++u) {
      float* op = out + ((size_t)b * COUT + orow0 + m * 16) * HW + col + u * 16;
      #pragma unroll
      for (int r = 0; r < 4; ++r) op[(size_t)r * HW] = acc[m][u][r];
    }
  }
}

// ---------------- launcher -------------------------------------------------
extern "C" void kernel_launch(void* const* d_in, const int* in_sizes, int n_in,
                              void* d_out, int out_size, void* d_ws, size_t ws_size,
                              hipStream_t stream) {
  const float* x        = (const float*)d_in[0];
  const float* gate_w   = (const float*)d_in[1];
  const float* gate_b   = (const float*)d_in[2];
  const float* expert_w = (const float*)d_in[3];
  float* out = (float*)d_out;

  char* ws = (char*)d_ws;
  uint4* weff   = (uint4*)ws;                               // 33,554,432 B
  uint4* xt     = (uint4*)(ws + 33554432);                  // 51,380,224 B
  float* parts  = (float*)(ws + 33554432 + 51380224);       //    917,504 B
  float* g      = (float*)(ws + 33554432 + 51380224 + 917504);  //  2,048 B

  xtpool_kernel<<<7168, 256, 0, stream>>>(x, xt, parts);
  gate_kernel<<<1, 512, 0, stream>>>(parts, gate_w, gate_b, g);
  weff_kernel<<<dim3(32, 4), 256, 0, stream>>>(expert_w, g, weff);
  gemm_kernel<<<896, 256, 0, stream>>>(weff, xt, out);
}

// Round 6
// 94.219 us; speedup vs baseline: 2.7443x; 1.8201x over previous
//
#include <hip/hip_runtime.h>

// Problem constants: B=64, Cin=512, Cout=512, H=W=28 (HW=784), K=8 experts.
#define NB 64
#define CIN 512
#define COUT 512
#define HW 784
#define KEXP 8

typedef __attribute__((ext_vector_type(8))) short bf16x8;   // 8 bf16 = 4 VGPR (MFMA A/B frag)
typedef __attribute__((ext_vector_type(4))) float f32x4;    // MFMA C/D frag

typedef const __attribute__((address_space(1))) unsigned int GU32;
typedef __attribute__((address_space(3))) unsigned int LU32;

__device__ __forceinline__ unsigned f2bf1(float f) {
  unsigned u = __builtin_bit_cast(unsigned, f);
  return (u + 0x7FFFu + ((u >> 16) & 1u)) >> 16;   // RNE fp32->bf16
}
__device__ __forceinline__ unsigned f2bf2(float lo, float hi) {
  return f2bf1(lo) | (f2bf1(hi) << 16);
}

// ---------------- Kernel 1: fused transpose(x)->bf16-tiled + pooled parts --
// Grid 7168 = (b*7+nb)*16 + kk. Per block: one 32x112 tile of x[b] ->
//   xt[((b*7+nb)*16+kk)*448 + u], u=kgrp*112+col packs
//   x[b][kk*32+kgrp*8+j][nb*112+col], j=0..7 (k-contiguous bf16x8).
// Plus pooled partials parts[nb][b][kk*32+r] (sum over the 112 cols).
__global__ __launch_bounds__(256) void xtpool_kernel(const float* __restrict__ x,
                                                     uint4* __restrict__ xt,
                                                     float* __restrict__ parts) {
  __shared__ float tile[32][113];
  int id = blockIdx.x;
  int kk = id & 15, bn = id >> 4;
  int b = bn / 7, nb = bn - b * 7;
  const float* xsrc = x + (size_t)b * (CIN * HW) + (size_t)kk * 32 * HW + nb * 112;
  uint4* dst = xt + (size_t)id * 448;
  int t = threadIdx.x;

  #pragma unroll
  for (int i = 0; i < 14; ++i) {
    int idx = t + i * 256;                          // 0..3583
    int r = idx / 112, cc = idx - r * 112;
    tile[r][cc] = xsrc[(size_t)r * HW + cc];
  }
  __syncthreads();

  // pooled partial: row pr, threads pp=0..7 each sum 14 cols, shfl-reduce
  {
    int pr = t >> 3, pp = t & 7;
    float s = 0.f;
    #pragma unroll
    for (int i = 0; i < 14; ++i) s += tile[pr][pp * 14 + i];
    s += __shfl_xor(s, 1); s += __shfl_xor(s, 2); s += __shfl_xor(s, 4);
    if (pp == 0) parts[((size_t)nb * NB + b) * CIN + kk * 32 + pr] = s;
  }

  // pack units (k-contiguous bf16x8), natural slot order
  {
    int k0 = t / 112, c0 = t - k0 * 112;
    uint4 pk;
    pk.x = f2bf2(tile[k0 * 8 + 0][c0], tile[k0 * 8 + 1][c0]);
    pk.y = f2bf2(tile[k0 * 8 + 2][c0], tile[k0 * 8 + 3][c0]);
    pk.z = f2bf2(tile[k0 * 8 + 4][c0], tile[k0 * 8 + 5][c0]);
    pk.w = f2bf2(tile[k0 * 8 + 6][c0], tile[k0 * 8 + 7][c0]);
    dst[t] = pk;
  }
  if (t < 192) {
    int t2 = 256 + t, k1 = t2 / 112, c1 = t2 - k1 * 112;
    uint4 pk;
    pk.x = f2bf2(tile[k1 * 8 + 0][c1], tile[k1 * 8 + 1][c1]);
    pk.y = f2bf2(tile[k1 * 8 + 2][c1], tile[k1 * 8 + 3][c1]);
    pk.z = f2bf2(tile[k1 * 8 + 4][c1], tile[k1 * 8 + 5][c1]);
    pk.w = f2bf2(tile[k1 * 8 + 6][c1], tile[k1 * 8 + 7][c1]);
    dst[256 + t] = pk;
  }
}

// ---------------- Kernel 2: gate (per-batch block) + local sparsemax -------
// 64 blocks x 256 threads. Block b: pooled[c] = sum_q parts[q][b][c] for
// c = t, t+256 (coalesced); 8 logit partials per thread; wave-shfl + LDS
// combine; thread 0 runs the K=8 sparsemax and writes g[b][0..7].
__global__ __launch_bounds__(256) void gate_kernel(const float* __restrict__ parts,
                                                   const float* __restrict__ gw,
                                                   const float* __restrict__ gb,
                                                   float* __restrict__ g) {
  __shared__ float red[4][KEXP];
  int b = blockIdx.x;
  int t = threadIdx.x;
  int lane = t & 63, w = t >> 6;

  float p0 = 0.f, p1 = 0.f;
  #pragma unroll
  for (int q = 0; q < 7; ++q) {
    const float* pr = parts + (size_t)q * (NB * CIN) + b * CIN;
    p0 += pr[t];
    p1 += pr[t + 256];
  }
  float zk[KEXP];
  #pragma unroll
  for (int k = 0; k < KEXP; ++k)
    zk[k] = p0 * gw[k * CIN + t] + p1 * gw[k * CIN + t + 256];

  #pragma unroll
  for (int k = 0; k < KEXP; ++k) {
    float s = zk[k];
    #pragma unroll
    for (int off = 32; off; off >>= 1) s += __shfl_down(s, off);
    if (lane == 0) red[w][k] = s;
  }
  __syncthreads();

  if (t == 0) {
    float z[8], zs[8];
    #pragma unroll
    for (int j = 0; j < 8; ++j) {
      z[j] = (red[0][j] + red[1][j] + red[2][j] + red[3][j]) * (1.0f / 784.0f) + gb[j];
      zs[j] = z[j];
    }
    #pragma unroll
    for (int a = 1; a < 8; ++a) {
      float v = zs[a]; int j = a;
      while (j > 0 && zs[j - 1] < v) { zs[j] = zs[j - 1]; --j; }
      zs[j] = v;
    }
    float cums[8]; float csum = 0.f;
    #pragma unroll
    for (int j = 0; j < 8; ++j) { csum += zs[j]; cums[j] = csum; }
    int kz = 0;
    #pragma unroll
    for (int j = 0; j < 8; ++j)
      if (1.0f + (float)(j + 1) * zs[j] > cums[j]) kz = j + 1;
    float tau = (cums[kz - 1] - 1.0f) / (float)kz;
    #pragma unroll
    for (int j = 0; j < 8; ++j) g[b * 8 + j] = fmaxf(z[j] - tau, 0.0f);
  }
}

// ---------------- Kernel 3: w_eff builder (bf16, BM=256 GEMM-tiled) -------
// unit(b,o,i) = b*32768 + ((o>>8)*16 + (i>>5))*1024 + ((i>>3)&3)*256 + (o&255)
__global__ __launch_bounds__(256) void weff_kernel(const float* __restrict__ E,
                                                   const float* __restrict__ g,
                                                   uint4* __restrict__ wt) {
  __shared__ float gs[NB * KEXP];
  int t = threadIdx.x;
  ((float2*)gs)[t] = ((const float2*)g)[t];
  int o = blockIdx.x * 16 + (t & 15);
  int i = blockIdx.y * 128 + (t >> 4) * 8;
  float e[8][8];
  #pragma unroll
  for (int k = 0; k < 8; ++k) {
    const float4* p = (const float4*)(E + (size_t)k * (COUT * CIN) + (size_t)o * CIN + i);
    float4 a = p[0], c = p[1];
    e[k][0] = a.x; e[k][1] = a.y; e[k][2] = a.z; e[k][3] = a.w;
    e[k][4] = c.x; e[k][5] = c.y; e[k][6] = c.z; e[k][7] = c.w;
  }
  __syncthreads();
  int base = ((o >> 8) * 16 + (i >> 5)) * 1024 + ((i >> 3) & 3) * 256 + (o & 255);
  for (int b = 0; b < NB; ++b) {
    float acc[8] = {0, 0, 0, 0, 0, 0, 0, 0};
    #pragma unroll
    for (int k = 0; k < 8; ++k) {
      float gv = gs[b * 8 + k];
      #pragma unroll
      for (int j = 0; j < 8; ++j) acc[j] += gv * e[k][j];
    }
    uint4 pk;
    pk.x = f2bf2(acc[0], acc[1]); pk.y = f2bf2(acc[2], acc[3]);
    pk.z = f2bf2(acc[4], acc[5]); pk.w = f2bf2(acc[6], acc[7]);
    wt[(size_t)base + (size_t)b * 32768] = pk;
  }
}

// ---------------- Kernel 4: batched GEMM, BM=256 x BN=112, BK=32 ----------
// All staging via global_load_lds (A natural, B source pre-swizzled), 2-phase
// double-buffered pipeline: STAGE(kk+1) issued before compute(kk), one
// vmcnt(0)+barrier per kk.
__global__ __launch_bounds__(256) void gemm_kernel(const uint4* __restrict__ weff,
                                                   const uint4* __restrict__ xt,
                                                   float* __restrict__ out) {
  __shared__ uint4 ldsA[2][1024];  // [kgrp4][row256] (16KB each)
  __shared__ uint4 ldsB[2][448];   // [kgrp4][col112], XOR-swizzled (7KB each)
  int id = blockIdx.x;
  int xcd = id & 7, s = id >> 3;
  int bloc = s / 14, inner = s - bloc * 14;
  int b = xcd * 8 + bloc;
  int mb = inner & 1, nb = inner >> 1;

  int t = threadIdx.x;
  int lane = t & 63, w = t >> 6;
  int l15 = lane & 15, l4 = lane >> 4;

  const uint4* asrc = weff + (size_t)b * 32768 + (size_t)mb * 16384;
  const uint4* bsrc = xt + (size_t)(b * 7 + nb) * 7168;

  int s1 = w * 64 + lane,       fs1 = s1 ^ ((s1 >> 3) & 7);
  int s2 = 256 + w * 64 + lane, fs2 = s2 ^ ((s2 >> 3) & 7);

  f32x4 acc[4][7] = {};

#define STAGE(buf, kk)                                                          \
  do {                                                                          \
    _Pragma("unroll")                                                           \
    for (int it = 0; it < 4; ++it)                                              \
      __builtin_amdgcn_global_load_lds((GU32*)(asrc + (kk) * 1024 + it * 256 + t), \
                                       (LU32*)(&ldsA[buf][it * 256 + w * 64]), 16, 0, 0); \
    __builtin_amdgcn_global_load_lds((GU32*)(bsrc + (kk) * 448 + fs1),          \
                                     (LU32*)(&ldsB[buf][w * 64]), 16, 0, 0);    \
    if (w < 3)                                                                  \
      __builtin_amdgcn_global_load_lds((GU32*)(bsrc + (kk) * 448 + fs2),        \
                                       (LU32*)(&ldsB[buf][256 + w * 64]), 16, 0, 0); \
  } while (0)

  STAGE(0, 0);
  asm volatile("s_waitcnt vmcnt(0)");
  __syncthreads();

  for (int kk = 0; kk < 16; ++kk) {
    int cur = kk & 1;
    if (kk < 15) STAGE(cur ^ 1, kk + 1);

    bf16x8 af[4];
    #pragma unroll
    for (int m = 0; m < 4; ++m)
      af[m] = *(const bf16x8*)&ldsA[cur][l4 * 256 + w * 64 + m * 16 + l15];
    #pragma unroll
    for (int u = 0; u < 7; ++u) {
      int un = l4 * 112 + u * 16 + l15;
      bf16x8 bf = *(const bf16x8*)&ldsB[cur][un ^ ((un >> 3) & 7)];
      #pragma unroll
      for (int m = 0; m < 4; ++m)
        acc[m][u] = __builtin_amdgcn_mfma_f32_16x16x32_bf16(af[m], bf, acc[m][u], 0, 0, 0);
    }

    asm volatile("s_waitcnt vmcnt(0)");  // STAGE(kk+1) drained (hidden by MFMA)
    __syncthreads();
  }
#undef STAGE

  // epilogue: D layout col=lane&15, row=(lane>>4)*4+reg
  int orow0 = mb * 256 + w * 64 + l4 * 4;
  int col = nb * 112 + l15;
  #pragma unroll
  for (int m = 0; m < 4; ++m) {
    #pragma unroll
    for (int u = 0; u < 7; ++u) {
      float* op = out + ((size_t)b * COUT + orow0 + m * 16) * HW + col + u * 16;
      #pragma unroll
      for (int r = 0; r < 4; ++r) op[(size_t)r * HW] = acc[m][u][r];
    }
  }
}

// ---------------- launcher -------------------------------------------------
extern "C" void kernel_launch(void* const* d_in, const int* in_sizes, int n_in,
                              void* d_out, int out_size, void* d_ws, size_t ws_size,
                              hipStream_t stream) {
  const float* x        = (const float*)d_in[0];
  const float* gate_w   = (const float*)d_in[1];
  const float* gate_b   = (const float*)d_in[2];
  const float* expert_w = (const float*)d_in[3];
  float* out = (float*)d_out;

  char* ws = (char*)d_ws;
  uint4* weff   = (uint4*)ws;                               // 33,554,432 B
  uint4* xt     = (uint4*)(ws + 33554432);                  // 51,380,224 B
  float* parts  = (float*)(ws + 33554432 + 51380224);       //    917,504 B
  float* g      = (float*)(ws + 33554432 + 51380224 + 917504);  //  2,048 B

  xtpool_kernel<<<7168, 256, 0, stream>>>(x, xt, parts);
  gate_kernel<<<NB, 256, 0, stream>>>(parts, gate_w, gate_b, g);
  weff_kernel<<<dim3(32, 4), 256, 0, stream>>>(expert_w, g, weff);
  gemm_kernel<<<896, 256, 0, stream>>>(weff, xt, out);
}

// Round 7
// 91.079 us; speedup vs baseline: 2.8389x; 1.0345x over previous
//
#include <hip/hip_runtime.h>

// Problem constants: B=64, Cin=512, Cout=512, H=W=28 (HW=784), K=8 experts.
#define NB 64
#define CIN 512
#define COUT 512
#define HW 784
#define KEXP 8

typedef __attribute__((ext_vector_type(8))) short bf16x8;   // 8 bf16 = 4 VGPR (MFMA A/B frag)
typedef __attribute__((ext_vector_type(4))) float f32x4;    // MFMA C/D frag

typedef const __attribute__((address_space(1))) unsigned int GU32;
typedef __attribute__((address_space(3))) unsigned int LU32;

__device__ __forceinline__ unsigned f2bf1(float f) {
  unsigned u = __builtin_bit_cast(unsigned, f);
  return (u + 0x7FFFu + ((u >> 16) & 1u)) >> 16;   // RNE fp32->bf16
}
__device__ __forceinline__ unsigned f2bf2(float lo, float hi) {
  return f2bf1(lo) | (f2bf1(hi) << 16);
}

// ---------------- Kernel 1: fused transpose(x)->bf16-tiled + pooled parts --
// Grid 7168 = (b*7+nb)*16 + kk. Per block: one 32x112 tile of x[b] ->
//   xt[((b*7+nb)*16+kk)*448 + u], u=kgrp*112+col packs
//   x[b][kk*32+kgrp*8+j][nb*112+col], j=0..7 (k-contiguous bf16x8).
// Plus pooled partials parts[nb][b][kk*32+r] (sum over the 112 cols).
__global__ __launch_bounds__(256) void xtpool_kernel(const float* __restrict__ x,
                                                     uint4* __restrict__ xt,
                                                     float* __restrict__ parts) {
  __shared__ float tile[32][113];
  int id = blockIdx.x;
  int kk = id & 15, bn = id >> 4;
  int b = bn / 7, nb = bn - b * 7;
  const float* xsrc = x + (size_t)b * (CIN * HW) + (size_t)kk * 32 * HW + nb * 112;
  uint4* dst = xt + (size_t)id * 448;
  int t = threadIdx.x;

  #pragma unroll
  for (int i = 0; i < 14; ++i) {
    int idx = t + i * 256;                          // 0..3583
    int r = idx / 112, cc = idx - r * 112;
    tile[r][cc] = xsrc[(size_t)r * HW + cc];
  }
  __syncthreads();

  // pooled partial: row pr, threads pp=0..7 each sum 14 cols, shfl-reduce
  {
    int pr = t >> 3, pp = t & 7;
    float s = 0.f;
    #pragma unroll
    for (int i = 0; i < 14; ++i) s += tile[pr][pp * 14 + i];
    s += __shfl_xor(s, 1); s += __shfl_xor(s, 2); s += __shfl_xor(s, 4);
    if (pp == 0) parts[((size_t)nb * NB + b) * CIN + kk * 32 + pr] = s;
  }

  // pack units (k-contiguous bf16x8), natural slot order
  {
    int k0 = t / 112, c0 = t - k0 * 112;
    uint4 pk;
    pk.x = f2bf2(tile[k0 * 8 + 0][c0], tile[k0 * 8 + 1][c0]);
    pk.y = f2bf2(tile[k0 * 8 + 2][c0], tile[k0 * 8 + 3][c0]);
    pk.z = f2bf2(tile[k0 * 8 + 4][c0], tile[k0 * 8 + 5][c0]);
    pk.w = f2bf2(tile[k0 * 8 + 6][c0], tile[k0 * 8 + 7][c0]);
    dst[t] = pk;
  }
  if (t < 192) {
    int t2 = 256 + t, k1 = t2 / 112, c1 = t2 - k1 * 112;
    uint4 pk;
    pk.x = f2bf2(tile[k1 * 8 + 0][c1], tile[k1 * 8 + 1][c1]);
    pk.y = f2bf2(tile[k1 * 8 + 2][c1], tile[k1 * 8 + 3][c1]);
    pk.z = f2bf2(tile[k1 * 8 + 4][c1], tile[k1 * 8 + 5][c1]);
    pk.w = f2bf2(tile[k1 * 8 + 6][c1], tile[k1 * 8 + 7][c1]);
    dst[256 + t] = pk;
  }
}

// ---------------- Kernel 2: gate (per-batch block) + local sparsemax -------
__global__ __launch_bounds__(256) void gate_kernel(const float* __restrict__ parts,
                                                   const float* __restrict__ gw,
                                                   const float* __restrict__ gb,
                                                   float* __restrict__ g) {
  __shared__ float red[4][KEXP];
  int b = blockIdx.x;
  int t = threadIdx.x;
  int lane = t & 63, w = t >> 6;

  float p0 = 0.f, p1 = 0.f;
  #pragma unroll
  for (int q = 0; q < 7; ++q) {
    const float* pr = parts + (size_t)q * (NB * CIN) + b * CIN;
    p0 += pr[t];
    p1 += pr[t + 256];
  }
  float zk[KEXP];
  #pragma unroll
  for (int k = 0; k < KEXP; ++k)
    zk[k] = p0 * gw[k * CIN + t] + p1 * gw[k * CIN + t + 256];

  #pragma unroll
  for (int k = 0; k < KEXP; ++k) {
    float s = zk[k];
    #pragma unroll
    for (int off = 32; off; off >>= 1) s += __shfl_down(s, off);
    if (lane == 0) red[w][k] = s;
  }
  __syncthreads();

  if (t == 0) {
    float z[8], zs[8];
    #pragma unroll
    for (int j = 0; j < 8; ++j) {
      z[j] = (red[0][j] + red[1][j] + red[2][j] + red[3][j]) * (1.0f / 784.0f) + gb[j];
      zs[j] = z[j];
    }
    #pragma unroll
    for (int a = 1; a < 8; ++a) {
      float v = zs[a]; int j = a;
      while (j > 0 && zs[j - 1] < v) { zs[j] = zs[j - 1]; --j; }
      zs[j] = v;
    }
    float cums[8]; float csum = 0.f;
    #pragma unroll
    for (int j = 0; j < 8; ++j) { csum += zs[j]; cums[j] = csum; }
    int kz = 0;
    #pragma unroll
    for (int j = 0; j < 8; ++j)
      if (1.0f + (float)(j + 1) * zs[j] > cums[j]) kz = j + 1;
    float tau = (cums[kz - 1] - 1.0f) / (float)kz;
    #pragma unroll
    for (int j = 0; j < 8; ++j) g[b * 8 + j] = fmaxf(z[j] - tau, 0.0f);
  }
}

// ---------------- Kernel 3: w_eff builder (bf16, BM=256 GEMM-tiled) -------
// unit(b,o,i) = b*32768 + ((o>>8)*16 + (i>>5))*1024 + ((i>>3)&3)*256 + (o&255)
__global__ __launch_bounds__(256) void weff_kernel(const float* __restrict__ E,
                                                   const float* __restrict__ g,
                                                   uint4* __restrict__ wt) {
  __shared__ float gs[NB * KEXP];
  int t = threadIdx.x;
  ((float2*)gs)[t] = ((const float2*)g)[t];
  int o = blockIdx.x * 16 + (t & 15);
  int i = blockIdx.y * 128 + (t >> 4) * 8;
  float e[8][8];
  #pragma unroll
  for (int k = 0; k < 8; ++k) {
    const float4* p = (const float4*)(E + (size_t)k * (COUT * CIN) + (size_t)o * CIN + i);
    float4 a = p[0], c = p[1];
    e[k][0] = a.x; e[k][1] = a.y; e[k][2] = a.z; e[k][3] = a.w;
    e[k][4] = c.x; e[k][5] = c.y; e[k][6] = c.z; e[k][7] = c.w;
  }
  __syncthreads();
  int base = ((o >> 8) * 16 + (i >> 5)) * 1024 + ((i >> 3) & 3) * 256 + (o & 255);
  for (int b = 0; b < NB; ++b) {
    float acc[8] = {0, 0, 0, 0, 0, 0, 0, 0};
    #pragma unroll
    for (int k = 0; k < 8; ++k) {
      float gv = gs[b * 8 + k];
      #pragma unroll
      for (int j = 0; j < 8; ++j) acc[j] += gv * e[k][j];
    }
    uint4 pk;
    pk.x = f2bf2(acc[0], acc[1]); pk.y = f2bf2(acc[2], acc[3]);
    pk.z = f2bf2(acc[4], acc[5]); pk.w = f2bf2(acc[6], acc[7]);
    wt[(size_t)base + (size_t)b * 32768] = pk;
  }
}

// ---------------- Kernel 4: batched GEMM, BM=256 x BN=112, BK=32 ----------
// 8 waves (512 thr): wave w owns rows w*32..w*32+31 (2 m-frags). All staging
// via global_load_lds; double-buffered; STAGE(kk+1) issued before compute(kk);
// one vmcnt(0)+barrier per kk. 24 waves/CU hide the stage drain (m114).
__global__ __launch_bounds__(512) void gemm_kernel(const uint4* __restrict__ weff,
                                                   const uint4* __restrict__ xt,
                                                   float* __restrict__ out) {
  __shared__ uint4 ldsA[2][1024];  // [kgrp4][row256] (16KB each)
  __shared__ uint4 ldsB[2][448];   // [kgrp4][col112], XOR-swizzled (7KB each)
  int id = blockIdx.x;
  int xcd = id & 7, s = id >> 3;
  int bloc = s / 14, inner = s - bloc * 14;
  int b = xcd * 8 + bloc;
  int mb = inner & 1, nb = inner >> 1;

  int t = threadIdx.x;
  int lane = t & 63, w = t >> 6;          // 8 waves
  int l15 = lane & 15, l4 = lane >> 4;

  const uint4* asrc = weff + (size_t)b * 32768 + (size_t)mb * 16384;
  const uint4* bsrc = xt + (size_t)(b * 7 + nb) * 7168;

  // B glds: waves 0-6 fill slots w*64+lane; source pre-swizzled (involution).
  int s1 = w * 64 + lane, fs1 = s1 ^ ((s1 >> 3) & 7);

  f32x4 acc[2][7] = {};

#define STAGE(buf, kk)                                                          \
  do {                                                                          \
    _Pragma("unroll")                                                           \
    for (int it = 0; it < 2; ++it)                                              \
      __builtin_amdgcn_global_load_lds((GU32*)(asrc + (kk) * 1024 + it * 512 + t), \
                                       (LU32*)(&ldsA[buf][it * 512 + w * 64]), 16, 0, 0); \
    if (w < 7)                                                                  \
      __builtin_amdgcn_global_load_lds((GU32*)(bsrc + (kk) * 448 + fs1),        \
                                       (LU32*)(&ldsB[buf][w * 64]), 16, 0, 0);  \
  } while (0)

  STAGE(0, 0);
  asm volatile("s_waitcnt vmcnt(0)");
  __syncthreads();

  for (int kk = 0; kk < 16; ++kk) {
    int cur = kk & 1;
    if (kk < 15) STAGE(cur ^ 1, kk + 1);

    bf16x8 af[2];
    #pragma unroll
    for (int m = 0; m < 2; ++m)
      af[m] = *(const bf16x8*)&ldsA[cur][l4 * 256 + w * 32 + m * 16 + l15];
    #pragma unroll
    for (int u = 0; u < 7; ++u) {
      int un = l4 * 112 + u * 16 + l15;
      bf16x8 bf = *(const bf16x8*)&ldsB[cur][un ^ ((un >> 3) & 7)];
      #pragma unroll
      for (int m = 0; m < 2; ++m)
        acc[m][u] = __builtin_amdgcn_mfma_f32_16x16x32_bf16(af[m], bf, acc[m][u], 0, 0, 0);
    }

    asm volatile("s_waitcnt vmcnt(0)");  // STAGE(kk+1) drained (hidden by MFMA+TLP)
    __syncthreads();
  }
#undef STAGE

  // epilogue: D layout col=lane&15, row=(lane>>4)*4+reg
  int orow0 = mb * 256 + w * 32 + l4 * 4;
  int col = nb * 112 + l15;
  #pragma unroll
  for (int m = 0; m < 2; ++m) {
    #pragma unroll
    for (int u = 0; u < 7; ++u) {
      float* op = out + ((size_t)b * COUT + orow0 + m * 16) * HW + col + u * 16;
      #pragma unroll
      for (int r = 0; r < 4; ++r) op[(size_t)r * HW] = acc[m][u][r];
    }
  }
}

// ---------------- launcher -------------------------------------------------
extern "C" void kernel_launch(void* const* d_in, const int* in_sizes, int n_in,
                              void* d_out, int out_size, void* d_ws, size_t ws_size,
                              hipStream_t stream) {
  const float* x        = (const float*)d_in[0];
  const float* gate_w   = (const float*)d_in[1];
  const float* gate_b   = (const float*)d_in[2];
  const float* expert_w = (const float*)d_in[3];
  float* out = (float*)d_out;

  char* ws = (char*)d_ws;
  uint4* weff   = (uint4*)ws;                               // 33,554,432 B
  uint4* xt     = (uint4*)(ws + 33554432);                  // 51,380,224 B
  float* parts  = (float*)(ws + 33554432 + 51380224);       //    917,504 B
  float* g      = (float*)(ws + 33554432 + 51380224 + 917504);  //  2,048 B

  xtpool_kernel<<<7168, 256, 0, stream>>>(x, xt, parts);
  gate_kernel<<<NB, 256, 0, stream>>>(parts, gate_w, gate_b, g);
  weff_kernel<<<dim3(32, 4), 256, 0, stream>>>(expert_w, g, weff);
  gemm_kernel<<<896, 512, 0, stream>>>(weff, xt, out);
}

// Round 8
// 90.860 us; speedup vs baseline: 2.8457x; 1.0024x over previous
//
#include <hip/hip_runtime.h>

// Problem constants: B=64, Cin=512, Cout=512, H=W=28 (HW=784), K=8 experts.
#define NB 64
#define CIN 512
#define COUT 512
#define HW 784
#define KEXP 8

typedef __attribute__((ext_vector_type(8))) short bf16x8;   // 8 bf16 = 4 VGPR (MFMA A/B frag)
typedef __attribute__((ext_vector_type(4))) float f32x4;    // MFMA C/D frag

typedef const __attribute__((address_space(1))) unsigned int GU32;
typedef __attribute__((address_space(3))) unsigned int LU32;

__device__ __forceinline__ unsigned f2bf1(float f) {
  unsigned u = __builtin_bit_cast(unsigned, f);
  return (u + 0x7FFFu + ((u >> 16) & 1u)) >> 16;   // RNE fp32->bf16
}
__device__ __forceinline__ unsigned f2bf2(float lo, float hi) {
  return f2bf1(lo) | (f2bf1(hi) << 16);
}

// ---------------- Kernel 1: fused transpose(x)->bf16-tiled + pooled parts --
// Grid 7168 = (b*7+nb)*16 + kk. Per block: one 32x112 tile of x[b] ->
//   xt[((b*7+nb)*16+kk)*448 + u], u=kgrp*112+col packs
//   x[b][kk*32+kgrp*8+j][nb*112+col], j=0..7 (k-contiguous bf16x8).
// Plus pooled partials parts[nb][b][kk*32+r] (sum over the 112 cols).
__global__ __launch_bounds__(256) void xtpool_kernel(const float* __restrict__ x,
                                                     uint4* __restrict__ xt,
                                                     float* __restrict__ parts) {
  __shared__ float tile[32][113];
  int id = blockIdx.x;
  int kk = id & 15, bn = id >> 4;
  int b = bn / 7, nb = bn - b * 7;
  const float* xsrc = x + (size_t)b * (CIN * HW) + (size_t)kk * 32 * HW + nb * 112;
  uint4* dst = xt + (size_t)id * 448;
  int t = threadIdx.x;

  #pragma unroll
  for (int i = 0; i < 14; ++i) {
    int idx = t + i * 256;                          // 0..3583
    int r = idx / 112, cc = idx - r * 112;
    tile[r][cc] = xsrc[(size_t)r * HW + cc];
  }
  __syncthreads();

  // pooled partial: row pr, threads pp=0..7 each sum 14 cols, shfl-reduce
  {
    int pr = t >> 3, pp = t & 7;
    float s = 0.f;
    #pragma unroll
    for (int i = 0; i < 14; ++i) s += tile[pr][pp * 14 + i];
    s += __shfl_xor(s, 1); s += __shfl_xor(s, 2); s += __shfl_xor(s, 4);
    if (pp == 0) parts[((size_t)nb * NB + b) * CIN + kk * 32 + pr] = s;
  }

  // pack units (k-contiguous bf16x8), natural slot order
  {
    int k0 = t / 112, c0 = t - k0 * 112;
    uint4 pk;
    pk.x = f2bf2(tile[k0 * 8 + 0][c0], tile[k0 * 8 + 1][c0]);
    pk.y = f2bf2(tile[k0 * 8 + 2][c0], tile[k0 * 8 + 3][c0]);
    pk.z = f2bf2(tile[k0 * 8 + 4][c0], tile[k0 * 8 + 5][c0]);
    pk.w = f2bf2(tile[k0 * 8 + 6][c0], tile[k0 * 8 + 7][c0]);
    dst[t] = pk;
  }
  if (t < 192) {
    int t2 = 256 + t, k1 = t2 / 112, c1 = t2 - k1 * 112;
    uint4 pk;
    pk.x = f2bf2(tile[k1 * 8 + 0][c1], tile[k1 * 8 + 1][c1]);
    pk.y = f2bf2(tile[k1 * 8 + 2][c1], tile[k1 * 8 + 3][c1]);
    pk.z = f2bf2(tile[k1 * 8 + 4][c1], tile[k1 * 8 + 5][c1]);
    pk.w = f2bf2(tile[k1 * 8 + 6][c1], tile[k1 * 8 + 7][c1]);
    dst[256 + t] = pk;
  }
}

// ---------------- Kernel 2: gate (per-batch block) + local sparsemax -------
__global__ __launch_bounds__(256) void gate_kernel(const float* __restrict__ parts,
                                                   const float* __restrict__ gw,
                                                   const float* __restrict__ gb,
                                                   float* __restrict__ g) {
  __shared__ float red[4][KEXP];
  int b = blockIdx.x;
  int t = threadIdx.x;
  int lane = t & 63, w = t >> 6;

  float p0 = 0.f, p1 = 0.f;
  #pragma unroll
  for (int q = 0; q < 7; ++q) {
    const float* pr = parts + (size_t)q * (NB * CIN) + b * CIN;
    p0 += pr[t];
    p1 += pr[t + 256];
  }
  float zk[KEXP];
  #pragma unroll
  for (int k = 0; k < KEXP; ++k)
    zk[k] = p0 * gw[k * CIN + t] + p1 * gw[k * CIN + t + 256];

  #pragma unroll
  for (int k = 0; k < KEXP; ++k) {
    float s = zk[k];
    #pragma unroll
    for (int off = 32; off; off >>= 1) s += __shfl_down(s, off);
    if (lane == 0) red[w][k] = s;
  }
  __syncthreads();

  if (t == 0) {
    float z[8], zs[8];
    #pragma unroll
    for (int j = 0; j < 8; ++j) {
      z[j] = (red[0][j] + red[1][j] + red[2][j] + red[3][j]) * (1.0f / 784.0f) + gb[j];
      zs[j] = z[j];
    }
    #pragma unroll
    for (int a = 1; a < 8; ++a) {
      float v = zs[a]; int j = a;
      while (j > 0 && zs[j - 1] < v) { zs[j] = zs[j - 1]; --j; }
      zs[j] = v;
    }
    float cums[8]; float csum = 0.f;
    #pragma unroll
    for (int j = 0; j < 8; ++j) { csum += zs[j]; cums[j] = csum; }
    int kz = 0;
    #pragma unroll
    for (int j = 0; j < 8; ++j)
      if (1.0f + (float)(j + 1) * zs[j] > cums[j]) kz = j + 1;
    float tau = (cums[kz - 1] - 1.0f) / (float)kz;
    #pragma unroll
    for (int j = 0; j < 8; ++j) g[b * 8 + j] = fmaxf(z[j] - tau, 0.0f);
  }
}

// ---------------- Kernel 3: w_eff builder (bf16, BM=256 GEMM-tiled) -------
// unit(b,o,i) = b*32768 + ((o>>8)*16 + (i>>5))*1024 + ((i>>3)&3)*256 + (o&255)
// Grid dim3(32,4,2): z splits batches (32 each) -> 256 blocks (1/CU).
__global__ __launch_bounds__(256) void weff_kernel(const float* __restrict__ E,
                                                   const float* __restrict__ g,
                                                   uint4* __restrict__ wt) {
  __shared__ float gs[NB * KEXP];
  int t = threadIdx.x;
  ((float2*)gs)[t] = ((const float2*)g)[t];
  int o = blockIdx.x * 16 + (t & 15);
  int i = blockIdx.y * 128 + (t >> 4) * 8;
  int b0 = blockIdx.z * 32;
  float e[8][8];
  #pragma unroll
  for (int k = 0; k < 8; ++k) {
    const float4* p = (const float4*)(E + (size_t)k * (COUT * CIN) + (size_t)o * CIN + i);
    float4 a = p[0], c = p[1];
    e[k][0] = a.x; e[k][1] = a.y; e[k][2] = a.z; e[k][3] = a.w;
    e[k][4] = c.x; e[k][5] = c.y; e[k][6] = c.z; e[k][7] = c.w;
  }
  __syncthreads();
  int base = ((o >> 8) * 16 + (i >> 5)) * 1024 + ((i >> 3) & 3) * 256 + (o & 255);
  for (int b = b0; b < b0 + 32; ++b) {
    float acc[8] = {0, 0, 0, 0, 0, 0, 0, 0};
    #pragma unroll
    for (int k = 0; k < 8; ++k) {
      float gv = gs[b * 8 + k];
      #pragma unroll
      for (int j = 0; j < 8; ++j) acc[j] += gv * e[k][j];
    }
    uint4 pk;
    pk.x = f2bf2(acc[0], acc[1]); pk.y = f2bf2(acc[2], acc[3]);
    pk.z = f2bf2(acc[4], acc[5]); pk.w = f2bf2(acc[6], acc[7]);
    wt[(size_t)base + (size_t)b * 32768] = pk;
  }
}

// ---------------- Kernel 4: batched GEMM, BM=256 x BN=112, BK=32 ----------
// 8 waves; depth-2 counted-vmcnt pipeline over 3 LDS buffers: stage kk+1
// stays in flight across the barrier (vmcnt(3), never 0 mid-loop); STAGE(kk+2)
// issued after the barrier. Raw s_barrier (no __syncthreads drain).
#define VMCNT(n) asm volatile("s_waitcnt vmcnt(" #n ")" ::: "memory")
__global__ __launch_bounds__(512) void gemm_kernel(const uint4* __restrict__ weff,
                                                   const uint4* __restrict__ xt,
                                                   float* __restrict__ out) {
  __shared__ uint4 ldsA[3][1024];  // [kgrp4][row256] (16KB each)
  __shared__ uint4 ldsB[3][448];   // [kgrp4][col112], XOR-swizzled (7KB each)
  int id = blockIdx.x;
  int xcd = id & 7, s = id >> 3;
  int bloc = s / 14, inner = s - bloc * 14;
  int b = xcd * 8 + bloc;
  int mb = inner & 1, nb = inner >> 1;

  int t = threadIdx.x;
  int lane = t & 63, w = t >> 6;          // 8 waves
  int l15 = lane & 15, l4 = lane >> 4;

  const uint4* asrc = weff + (size_t)b * 32768 + (size_t)mb * 16384;
  const uint4* bsrc = xt + (size_t)(b * 7 + nb) * 7168;

  // B glds: waves 0-6 fill slots w*64+lane; source pre-swizzled (involution).
  int s1 = w * 64 + lane, fs1 = s1 ^ ((s1 >> 3) & 7);

  f32x4 acc[2][7] = {};

#define STAGE(buf, kk)                                                          \
  do {                                                                          \
    _Pragma("unroll")                                                           \
    for (int it = 0; it < 2; ++it)                                              \
      __builtin_amdgcn_global_load_lds((GU32*)(asrc + (kk) * 1024 + it * 512 + t), \
                                       (LU32*)(&ldsA[buf][it * 512 + w * 64]), 16, 0, 0); \
    if (w < 7)                                                                  \
      __builtin_amdgcn_global_load_lds((GU32*)(bsrc + (kk) * 448 + fs1),        \
                                       (LU32*)(&ldsB[buf][w * 64]), 16, 0, 0);  \
  } while (0)

  STAGE(0, 0);
  STAGE(1, 1);

  int cur = 0;
  for (int kk = 0; kk < 16; ++kk) {
    // wait: stage kk complete; stage kk+1 (3 loads: 2A+1B; wave 7: 2A) stays
    // in flight. Last iteration: nothing behind -> full drain.
    if (kk < 15) {
      if (w < 7) VMCNT(3); else VMCNT(2);
    } else {
      VMCNT(0);
    }
    __builtin_amdgcn_s_barrier();
    __builtin_amdgcn_sched_barrier(0);   // no hoist of ds_read above barrier

    if (kk < 14) {
      int nxt = cur + 2; if (nxt >= 3) nxt -= 3;
      STAGE(nxt, kk + 2);
    }

    bf16x8 af[2];
    #pragma unroll
    for (int m = 0; m < 2; ++m)
      af[m] = *(const bf16x8*)&ldsA[cur][l4 * 256 + w * 32 + m * 16 + l15];
    #pragma unroll
    for (int u = 0; u < 7; ++u) {
      int un = l4 * 112 + u * 16 + l15;
      bf16x8 bf = *(const bf16x8*)&ldsB[cur][un ^ ((un >> 3) & 7)];
      #pragma unroll
      for (int m = 0; m < 2; ++m)
        acc[m][u] = __builtin_amdgcn_mfma_f32_16x16x32_bf16(af[m], bf, acc[m][u], 0, 0, 0);
    }

    if (++cur >= 3) cur = 0;
  }
#undef STAGE

  // epilogue: D layout col=lane&15, row=(lane>>4)*4+reg
  int orow0 = mb * 256 + w * 32 + l4 * 4;
  int col = nb * 112 + l15;
  #pragma unroll
  for (int m = 0; m < 2; ++m) {
    #pragma unroll
    for (int u = 0; u < 7; ++u) {
      float* op = out + ((size_t)b * COUT + orow0 + m * 16) * HW + col + u * 16;
      #pragma unroll
      for (int r = 0; r < 4; ++r) op[(size_t)r * HW] = acc[m][u][r];
    }
  }
}

// ---------------- launcher -------------------------------------------------
extern "C" void kernel_launch(void* const* d_in, const int* in_sizes, int n_in,
                              void* d_out, int out_size, void* d_ws, size_t ws_size,
                              hipStream_t stream) {
  const float* x        = (const float*)d_in[0];
  const float* gate_w   = (const float*)d_in[1];
  const float* gate_b   = (const float*)d_in[2];
  const float* expert_w = (const float*)d_in[3];
  float* out = (float*)d_out;

  char* ws = (char*)d_ws;
  uint4* weff   = (uint4*)ws;                               // 33,554,432 B
  uint4* xt     = (uint4*)(ws + 33554432);                  // 51,380,224 B
  float* parts  = (float*)(ws + 33554432 + 51380224);       //    917,504 B
  float* g      = (float*)(ws + 33554432 + 51380224 + 917504);  //  2,048 B

  xtpool_kernel<<<7168, 256, 0, stream>>>(x, xt, parts);
  gate_kernel<<<NB, 256, 0, stream>>>(parts, gate_w, gate_b, g);
  weff_kernel<<<dim3(32, 4, 2), 256, 0, stream>>>(expert_w, g, weff);
  gemm_kernel<<<896, 512, 0, stream>>>(weff, xt, out);
}